// Round 7
// baseline (537.486 us; speedup 1.0000x reference)
//
#include <hip/hip_runtime.h>
#include <hip/hip_bf16.h>
#include <cstdint>

// GCN: 2-layer GraphConv + dense head on MI355X. Round 10:
//  - 5 dispatches: memset + prep1 + agg + gemm + tail2
//  - prep2 folded into prep1 (9 blocks recompute P1 in-LDS; hidden under the
//    ~100us cast phase). P1 buffer deleted.
//  - proj folded into GEMM epilogue: h-tile (regs) -> LDS bf16 -> dot with
//    W2aT/W2bT column slice -> int32 fixed-point partials uA[4][N1][10],
//    vA[4][N2][10]. hb never materialized (-40 MB traffic). int partials keep
//    slot-order replay determinism in tail2's edge sum.
//  - SLOT=64 slot-CSR + fused edge count&place in prep1 (R7/R8 evidence)

static constexpr int N0 = 100000;
static constexpr int N1 = 20000;
static constexpr int N2 = 4000;
static constexpr int HH = 512;
static constexpr int C  = 10;
static constexpr int M1PAD = 20096;  // 157 * 128
static constexpr int SLOT = 64;      // per-node adjacency capacity (deg~Pois(25))
static constexpr float FIX = 4194304.0f;     // 2^22
static constexpr float FIXINV = 1.0f / 4194304.0f;

using frag  = __attribute__((ext_vector_type(8))) short;
using f32x4 = __attribute__((ext_vector_type(4))) float;

__device__ inline float bf2f(unsigned short u) {
    unsigned t = ((unsigned)u) << 16; float f; __builtin_memcpy(&f, &t, 4); return f;
}
__device__ inline unsigned short f2bf(float f) {
    unsigned u; __builtin_memcpy(&u, &f, 4);
    u += 0x7FFFu + ((u >> 16) & 1u);  // RNE
    return (unsigned short)(u >> 16);
}
__device__ inline void gld16(const void* g, void* l) {
    __builtin_amdgcn_global_load_lds((const __attribute__((address_space(1))) void*)g,
                                     (__attribute__((address_space(3))) void*)l,
                                     16, 0, 0);
}

// ---- prep1: [0..7] W2aT/W2bT slices | [8] bout | [9..520] Wt transpose |
//             [521..] fused x-cast + edge count&place ----
__global__ __launch_bounds__(256)
void prep1_k(const int* __restrict__ src1, const int* __restrict__ dst1,
             const int* __restrict__ src2, const int* __restrict__ dst2,
             int* __restrict__ cnt1, int* __restrict__ cnt2,
             int* __restrict__ eidx1, int* __restrict__ eidx2,
             int E1, int E2,
             const float* __restrict__ x, unsigned short* __restrict__ xb,
             const float* __restrict__ Wrel1, const float* __restrict__ Wroot1,
             unsigned short* __restrict__ Wt,
             const float* __restrict__ Wrel2, const float* __restrict__ Wroot2,
             const float* __restrict__ Wlin, const float* __restrict__ Whead,
             const float* __restrict__ brel2, const float* __restrict__ blin,
             const float* __restrict__ bhead,
             float* __restrict__ W2aT, float* __restrict__ W2bT,
             float* __restrict__ bout,
             int epb) {
    __shared__ float sh[5120];   // 20 KB: Whead/P1 tile / transpose tile
    int b = blockIdx.x;
    const int tid = threadIdx.x;
    if (b < 9) {                 // ---- W2aT/W2bT slices (b<8) and bout (b==8) ----
        // Phase A: Whead -> LDS
        for (int i = tid; i < HH * C; i += 256) sh[i] = Whead[i];
        __syncthreads();
        // P1 rows j = tid, tid+256 into registers
        float p1r[2][C];
#pragma unroll
        for (int rr = 0; rr < 2; ++rr) {
            int j = tid + rr * 256;
            const float4* wl = (const float4*)(Wlin + (size_t)j * HH);
            float a[C];
#pragma unroll
            for (int c = 0; c < C; ++c) a[c] = 0.f;
            for (int m4 = 0; m4 < HH / 4; ++m4) {
                float4 v = wl[m4];
                int m = m4 * 4;
#pragma unroll
                for (int c = 0; c < C; ++c)
                    a[c] += v.x * sh[m * C + c] + v.y * sh[(m + 1) * C + c]
                          + v.z * sh[(m + 2) * C + c] + v.w * sh[(m + 3) * C + c];
            }
#pragma unroll
            for (int c = 0; c < C; ++c) p1r[rr][c] = a[c];
        }
        __syncthreads();
        // Phase B: LDS = P1
#pragma unroll
        for (int rr = 0; rr < 2; ++rr)
#pragma unroll
            for (int c = 0; c < C; ++c) sh[(tid + rr * 256) * C + c] = p1r[rr][c];
        __syncthreads();
        if (b < 8) {             // ---- Phase C: W2 slice [c][k-range 128] ----
            int z = b >> 2;
            int k = (b & 3) * 128 + (tid >> 1);
            int c0 = (tid & 1) * 5;
            const float* W = z ? Wroot2 : Wrel2;
            float* O = z ? W2bT : W2aT;
            const float4* wr = (const float4*)(W + (size_t)k * HH);
            float a[5] = {};
            for (int j4 = 0; j4 < HH / 4; ++j4) {
                float4 v = wr[j4];
                int j = j4 * 4;
#pragma unroll
                for (int cc = 0; cc < 5; ++cc) {
                    int c = c0 + cc;
                    a[cc] += v.x * sh[j * C + c] + v.y * sh[(j + 1) * C + c]
                           + v.z * sh[(j + 2) * C + c] + v.w * sh[(j + 3) * C + c];
                }
            }
#pragma unroll
            for (int cc = 0; cc < 5; ++cc) O[(c0 + cc) * HH + k] = a[cc];
        } else {                 // ---- bout ----
            float pr[C];
#pragma unroll
            for (int c = 0; c < C; ++c) pr[c] = 0.f;
#pragma unroll
            for (int rr = 0; rr < 2; ++rr) {
                int j = tid + rr * 256;
                float br = brel2[j], bl = blin[j];
#pragma unroll
                for (int c = 0; c < C; ++c)
                    pr[c] += br * sh[j * C + c] + bl * Whead[j * C + c];
            }
#pragma unroll
            for (int c = 0; c < C; ++c)
#pragma unroll
                for (int off = 32; off; off >>= 1) pr[c] += __shfl_xor(pr[c], off);
            __syncthreads();
            int wv = tid >> 6, ln = tid & 63;
            if (ln == 0)
#pragma unroll
                for (int c = 0; c < C; ++c) sh[wv * C + c] = pr[c];
            __syncthreads();
            if (tid < C) {
                float acc = bhead[tid];
#pragma unroll
                for (int w = 0; w < 4; ++w) acc += sh[w * C + tid];
                bout[tid] = acc;
            }
        }
        return;
    }
    b -= 9;
    if (b < 512) {                           // ---- weight transpose+cast ----
        int z = b >> 8, rem = b & 255;
        int bx = (rem & 15) * 32, by = (rem >> 4) * 32;
        const float* W = z ? Wroot1 : Wrel1;
        unsigned short* O = Wt + (size_t)z * HH * HH;
        int tx = tid & 31, ty = tid >> 5;
#pragma unroll
        for (int i = 0; i < 4; ++i)
            sh[(ty + i * 8) * 33 + tx] = W[(size_t)(by + ty + i * 8) * HH + bx + tx];
        __syncthreads();
#pragma unroll
        for (int i = 0; i < 4; ++i)
            O[(size_t)(bx + ty + i * 8) * HH + by + tx] = f2bf(sh[tx * 33 + ty + i * 8]);
        return;
    }
    b -= 512;
    {                   // ---- fused: edge count&place (epb/blk) + x cast ----
        int eg = b * epb + tid;
        bool hasE = (tid < epb) && (eg < E1 + E2);
        if (hasE) {
            if (eg < E1) {
                int d = dst1[eg];
                int pos = atomicAdd(&cnt1[d], 1);
                if (pos < SLOT) eidx1[d * SLOT + pos] = src1[eg];
            } else {
                int g2 = eg - E1;
                int d = dst2[g2];
                int pos = atomicAdd(&cnt2[d], 1);
                if (pos < SLOT) eidx2[d * SLOT + pos] = src2[g2];
            }
        }
        int g = b * 256 + tid;               // 16 floats per thread
        const float4* p = (const float4*)x + (size_t)g * 4;
        float4 v0 = p[0], v1 = p[1], v2 = p[2], v3 = p[3];
        unsigned short t[16] = {f2bf(v0.x), f2bf(v0.y), f2bf(v0.z), f2bf(v0.w),
                                f2bf(v1.x), f2bf(v1.y), f2bf(v1.z), f2bf(v1.w),
                                f2bf(v2.x), f2bf(v2.y), f2bf(v2.z), f2bf(v2.w),
                                f2bf(v3.x), f2bf(v3.y), f2bf(v3.z), f2bf(v3.w)};
        uint4* o = (uint4*)(xb + (size_t)g * 16);
        o[0] = ((const uint4*)t)[0];
        o[1] = ((const uint4*)t)[1];
    }
}

// ---- aggregation: one wave per node, slot CSR, int32 fixed-point (x2^20) ----
__global__ __launch_bounds__(256)
void agg_bf16_k(const unsigned short* __restrict__ x, const int* __restrict__ cnt,
                const int* __restrict__ eidx, unsigned short* __restrict__ out, int n) {
    int node = blockIdx.x * 4 + (threadIdx.x >> 6);
    if (node >= n) return;
    int l = threadIdx.x & 63;
    int deg = min(cnt[node], SLOT);
    const int* ep = eidx + (size_t)node * SLOT;
    int acc[8] = {};
    int i = 0;
    for (; i + 8 <= deg; i += 8) {
        uint4 v[8];
#pragma unroll
        for (int u = 0; u < 8; ++u)
            v[u] = *(const uint4*)(x + (size_t)ep[i + u] * HH + l * 8);
#pragma unroll
        for (int u = 0; u < 8; ++u) {
            const unsigned short* pv = (const unsigned short*)&v[u];
#pragma unroll
            for (int j = 0; j < 8; ++j) acc[j] += (int)(bf2f(pv[j]) * 1048576.0f);
        }
    }
    for (; i < deg; ++i) {
        uint4 a = *(const uint4*)(x + (size_t)ep[i] * HH + l * 8);
        const unsigned short* pa = (const unsigned short*)&a;
#pragma unroll
        for (int j = 0; j < 8; ++j) acc[j] += (int)(bf2f(pa[j]) * 1048576.0f);
    }
    unsigned short o[8];
#pragma unroll
    for (int j = 0; j < 8; ++j)
        o[j] = f2bf((float)acc[j] * (1.0f / 1048576.0f));
    *(uint4*)(out + (size_t)node * HH + l * 8) = *(const uint4*)o;
}

// ---- bf16 MFMA GEMM (layer 1, dual fused) + head-projection epilogue ----
// h = relu(agg1@Wrel1t + x@Wroot1t + b) computed per 128x128 tile; epilogue
// dots the bf16 h-tile against W2aT/W2bT column slices and emits int32
// fixed-point partials uA[part][N1][10], vA[part][N2][10]. h never hits HBM.
__global__ __launch_bounds__(256)
void gemm_mfma_k(const short* __restrict__ A1, const short* __restrict__ B1t,
                 const short* __restrict__ A2, const short* __restrict__ B2t,
                 const float* __restrict__ bias,
                 const float* __restrict__ W2aT, const float* __restrict__ W2bT,
                 int* __restrict__ uA, int* __restrict__ vA) {
    __shared__ __align__(16) short Ls[4 * 128 * 32];   // staging / h-tile (32 KB)
    __shared__ float wshA[C * 128], wshB[C * 128];     // W2 slices (10 KB)
    short* As1 = Ls;
    short* As2 = Ls + 4096;
    short* Bs1 = Ls + 8192;
    short* Bs2 = Ls + 12288;
    const int bn = blockIdx.x * 128;
    const int bm = blockIdx.y * 128;
    const int tid = threadIdx.x;
    const int lane = tid & 63;
    const int wave = tid >> 6;
    const int l15 = lane & 15;
    const int quad = lane >> 4;
    const int wm = (wave >> 1) * 64;
    const int wn = (wave & 1) * 64;
    const int r0 = tid >> 2;          // 0..63
    const int sg = (tid & 3) * 8;     // bf16 offset in 32-k row

    // stage W2 column slices (f32) — covered by the k-loop's first barrier
    for (int i = tid; i < C * 128; i += 256) {
        int c = i >> 7, k = i & 127;
        wshA[i] = W2aT[c * HH + bn + k];
        wshB[i] = W2bT[c * HH + bn + k];
    }

    f32x4 acc[4][4] = {};

    for (int k0 = 0; k0 < 512; k0 += 32) {
        gld16(A1 + (size_t)(bm + r0) * 512 + k0 + sg,        As1 + tid * 8);
        gld16(A1 + (size_t)(bm + r0 + 64) * 512 + k0 + sg,   As1 + (tid + 256) * 8);
        gld16(A2 + (size_t)(bm + r0) * 512 + k0 + sg,        As2 + tid * 8);
        gld16(A2 + (size_t)(bm + r0 + 64) * 512 + k0 + sg,   As2 + (tid + 256) * 8);
        gld16(B1t + (size_t)(bn + r0) * 512 + k0 + sg,       Bs1 + tid * 8);
        gld16(B1t + (size_t)(bn + r0 + 64) * 512 + k0 + sg,  Bs1 + (tid + 256) * 8);
        gld16(B2t + (size_t)(bn + r0) * 512 + k0 + sg,       Bs2 + tid * 8);
        gld16(B2t + (size_t)(bn + r0 + 64) * 512 + k0 + sg,  Bs2 + (tid + 256) * 8);
        __syncthreads();
        {
            frag a[4], b[4];
#pragma unroll
            for (int mi = 0; mi < 4; ++mi)
                a[mi] = *(const frag*)(As1 + (wm + mi * 16 + l15) * 32 + quad * 8);
#pragma unroll
            for (int ni = 0; ni < 4; ++ni)
                b[ni] = *(const frag*)(Bs1 + (wn + ni * 16 + l15) * 32 + quad * 8);
#pragma unroll
            for (int mi = 0; mi < 4; ++mi)
#pragma unroll
                for (int ni = 0; ni < 4; ++ni)
                    acc[mi][ni] = __builtin_amdgcn_mfma_f32_16x16x32_bf16(
                        a[mi], b[ni], acc[mi][ni], 0, 0, 0);
#pragma unroll
            for (int mi = 0; mi < 4; ++mi)
                a[mi] = *(const frag*)(As2 + (wm + mi * 16 + l15) * 32 + quad * 8);
#pragma unroll
            for (int ni = 0; ni < 4; ++ni)
                b[ni] = *(const frag*)(Bs2 + (wn + ni * 16 + l15) * 32 + quad * 8);
#pragma unroll
            for (int mi = 0; mi < 4; ++mi)
#pragma unroll
                for (int ni = 0; ni < 4; ++ni)
                    acc[mi][ni] = __builtin_amdgcn_mfma_f32_16x16x32_bf16(
                        a[mi], b[ni], acc[mi][ni], 0, 0, 0);
        }
        __syncthreads();
    }

    // ---- epilogue 1: h-tile (bias+relu, bf16) into LDS [128][128] ----
#pragma unroll
    for (int ni = 0; ni < 4; ++ni) {
        const int lc = wn + ni * 16 + l15;
        const float bv = bias[bn + lc];
#pragma unroll
        for (int mi = 0; mi < 4; ++mi) {
            const int lr0 = wm + mi * 16 + quad * 4;
#pragma unroll
            for (int r = 0; r < 4; ++r)
                Ls[(lr0 + r) * 128 + lc] = (short)f2bf(fmaxf(acc[mi][ni][r] + bv, 0.f));
        }
    }
    __syncthreads();

    // ---- epilogue 2: per-row dots vs W2 slices -> int partials ----
    const int lr = tid >> 1;
    const int half = tid & 1;
    const int gm = bm + lr;
    const bool doV = (gm < N2);
    float pu[C], pv[C];
#pragma unroll
    for (int c = 0; c < C; ++c) { pu[c] = 0.f; pv[c] = 0.f; }
    const uint4* hrow = (const uint4*)(Ls + lr * 128 + half * 64);
    for (int ch = 0; ch < 8; ++ch) {
        uint4 hv = hrow[ch];
        const unsigned short* ph = (const unsigned short*)&hv;
        float f[8];
#pragma unroll
        for (int j = 0; j < 8; ++j) f[j] = bf2f(ph[j]);
        const int cb = half * 64 + ch * 8;
#pragma unroll
        for (int c = 0; c < C; ++c) {
            const float* wa = &wshA[c * 128 + cb];
            float4 w0 = *(const float4*)wa, w1 = *(const float4*)(wa + 4);
            pu[c] += f[0] * w0.x + f[1] * w0.y + f[2] * w0.z + f[3] * w0.w
                   + f[4] * w1.x + f[5] * w1.y + f[6] * w1.z + f[7] * w1.w;
        }
        if (doV) {
#pragma unroll
            for (int c = 0; c < C; ++c) {
                const float* wb = &wshB[c * 128 + cb];
                float4 w0 = *(const float4*)wb, w1 = *(const float4*)(wb + 4);
                pv[c] += f[0] * w0.x + f[1] * w0.y + f[2] * w0.z + f[3] * w0.w
                       + f[4] * w1.x + f[5] * w1.y + f[6] * w1.z + f[7] * w1.w;
            }
        }
    }
#pragma unroll
    for (int c = 0; c < C; ++c) pu[c] += __shfl_xor(pu[c], 1);
#pragma unroll
    for (int c = 0; c < C; ++c) pv[c] += __shfl_xor(pv[c], 1);
    if (half == 0 && gm < N1) {
        int* up = uA + ((size_t)blockIdx.x * N1 + gm) * C;
#pragma unroll
        for (int c = 0; c < C; ++c) up[c] = (int)(pu[c] * FIX);
        if (doV) {
            int* vp = vA + ((size_t)blockIdx.x * N2 + gm) * C;
#pragma unroll
            for (int c = 0; c < C; ++c) vp[c] = (int)(pv[c] * FIX);
        }
    }
}

// ---- tail2: out[n][c] = fix(sum_edges sum_p uA) + fix(sum_p vA) + bout[c] ----
__global__ __launch_bounds__(256)
void tail2_k(const int* __restrict__ cnt2, const int* __restrict__ eidx2,
             const int* __restrict__ uA, const int* __restrict__ vA,
             const float* __restrict__ bout, float* __restrict__ out) {
    int t = blockIdx.x * 256 + threadIdx.x;
    if (t >= N2 * C) return;
    int n = t / C;
    int c = t - n * C;
    int deg = min(cnt2[n], SLOT);
    const int* ep = eidx2 + (size_t)n * SLOT;
    int acc = 0;
    for (int i = 0; i < deg; ++i) {
        int j = ep[i] * C + c;
        acc += uA[j] + uA[N1 * C + j] + uA[2 * N1 * C + j] + uA[3 * N1 * C + j];
    }
    int vacc = vA[t] + vA[N2 * C + t] + vA[2 * N2 * C + t] + vA[3 * N2 * C + t];
    out[t] = (float)acc * FIXINV + (float)vacc * FIXINV + bout[c];
}

extern "C" void kernel_launch(void* const* d_in, const int* in_sizes, int n_in,
                              void* d_out, int out_size, void* d_ws, size_t ws_size,
                              hipStream_t stream) {
    const float* x      = (const float*)d_in[0];
    const int*   src1   = (const int*)d_in[1];
    const int*   dst1   = (const int*)d_in[2];
    const int*   src2   = (const int*)d_in[3];
    const int*   dst2   = (const int*)d_in[4];
    const float* Wrel1  = (const float*)d_in[5];
    const float* brel1  = (const float*)d_in[6];
    const float* Wroot1 = (const float*)d_in[7];
    const float* Wrel2  = (const float*)d_in[8];
    const float* brel2  = (const float*)d_in[9];
    const float* Wroot2 = (const float*)d_in[10];
    const float* Wlin   = (const float*)d_in[11];
    const float* blin   = (const float*)d_in[12];
    const float* Whead  = (const float*)d_in[13];
    const float* bhead  = (const float*)d_in[14];
    float* out = (float*)d_out;

    const int E1 = in_sizes[1];
    const int E2 = in_sizes[3];

    // ---- workspace layout (~135 MB; ws ~800 MB) ----
    char* w = (char*)d_ws;
    auto alloc = [&](size_t bytes) { char* p = w; w += (bytes + 255) & ~(size_t)255; return p; };
    unsigned short* xb    = (unsigned short*)alloc((size_t)N0 * HH * 2);
    unsigned short* agg1b = (unsigned short*)alloc((size_t)M1PAD * HH * 2);
    unsigned short* Wt    = (unsigned short*)alloc((size_t)2 * HH * HH * 2);
    float* W2aT  = (float*)alloc((size_t)HH * C * 4);
    float* W2bT  = (float*)alloc((size_t)HH * C * 4);
    float* boutp = (float*)alloc(256);
    int*   uA    = (int*)alloc((size_t)4 * N1 * C * 4);
    int*   vA    = (int*)alloc((size_t)4 * N2 * C * 4);
    int* cnt1  = (int*)alloc((size_t)(N1 + N2) * 4);   // cnt1 | cnt2 contiguous
    int* cnt2  = cnt1 + N1;
    int* eidx1 = (int*)alloc((size_t)N1 * SLOT * 4);
    int* eidx2 = (int*)alloc((size_t)N2 * SLOT * 4);

    const short* Wrel1t  = (const short*)(Wt);
    const short* Wroot1t = (const short*)(Wt + (size_t)HH * HH);

    hipMemsetAsync(cnt1, 0, (size_t)(N1 + N2) * sizeof(int), stream);

    // ---- prep1: W2 slices + bout + castw + fused [castx + count&place] ----
    const int nbCast = N0 * HH / 16 / 256;   // 12500 (16 elem/thread)
    const int epb    = (E1 + E2 + nbCast - 1) / nbCast;   // ~48 edges per cast block
    prep1_k<<<9 + 512 + nbCast, 256, 0, stream>>>(
        src1, dst1, src2, dst2, cnt1, cnt2, eidx1, eidx2, E1, E2,
        x, xb, Wrel1, Wroot1, Wt, Wrel2, Wroot2, Wlin, Whead,
        brel2, blin, bhead, W2aT, W2bT, boutp, epb);

    // ---- layer 1 aggregation ----
    agg_bf16_k<<<(N1 + 3) / 4, 256, 0, stream>>>(xb, cnt1, eidx1, agg1b, N1);

    // ---- layer-1 GEMM + fused head projection ----
    {
        dim3 grid(HH / 128, M1PAD / 128);
        gemm_mfma_k<<<grid, 256, 0, stream>>>(
            (const short*)agg1b, Wrel1t, (const short*)xb, Wroot1t, brel1,
            W2aT, W2bT, uA, vA);
    }

    // ---- layer-2 aggregation over 10-dim int partials + epilogue ----
    tail2_k<<<(N2 * C + 255) / 256, 256, 0, stream>>>(cnt2, eidx2, uA, vA, boutp, out);
}

// Round 8
// 499.275 us; speedup vs baseline: 1.0765x; 1.0765x over previous
//
#include <hip/hip_runtime.h>
#include <hip/hip_bf16.h>
#include <cstdint>

// GCN: 2-layer GraphConv + dense head on MI355X. Round 11:
//  - REVERT R10's prep2-merge (regressed prep1 115->160us: low-parallelism W2
//    mega-blocks tail-extended the dispatch, VGPR 24->44, occ 78->22%).
//  - KEEP R10's proj-in-GEMM fusion (measured -11us on non-prep1 time):
//    GEMM epilogue dots the bf16 h-tile vs W2aT/W2bT slices -> int32 fixed
//    partials uA[4][N1][10], vA[4][N2][10]; hb never hits HBM.
//  - 6 dispatches: memset + prep1 + prep2 + agg + gemm + tail2
//  - SLOT=64 slot-CSR, fused edge count&place in prep1, int fixed-point
//    aggregation everywhere -> replay-deterministic without sorting.

static constexpr int N0 = 100000;
static constexpr int N1 = 20000;
static constexpr int N2 = 4000;
static constexpr int HH = 512;
static constexpr int C  = 10;
static constexpr int M1PAD = 20096;  // 157 * 128
static constexpr int SLOT = 64;      // per-node adjacency capacity (deg~Pois(25))
static constexpr float FIX = 4194304.0f;     // 2^22
static constexpr float FIXINV = 1.0f / 4194304.0f;

using frag  = __attribute__((ext_vector_type(8))) short;
using f32x4 = __attribute__((ext_vector_type(4))) float;

__device__ inline float bf2f(unsigned short u) {
    unsigned t = ((unsigned)u) << 16; float f; __builtin_memcpy(&f, &t, 4); return f;
}
__device__ inline unsigned short f2bf(float f) {
    unsigned u; __builtin_memcpy(&u, &f, 4);
    u += 0x7FFFu + ((u >> 16) & 1u);  // RNE
    return (unsigned short)(u >> 16);
}
__device__ inline void gld16(const void* g, void* l) {
    __builtin_amdgcn_global_load_lds((const __attribute__((address_space(1))) void*)g,
                                     (__attribute__((address_space(3))) void*)l,
                                     16, 0, 0);
}

// ---- prep1: P1 + weight cast + fused [x cast + edge count&place] (R9 form) ----
__global__ __launch_bounds__(256)
void prep1_k(const int* __restrict__ src1, const int* __restrict__ dst1,
             const int* __restrict__ src2, const int* __restrict__ dst2,
             int* __restrict__ cnt1, int* __restrict__ cnt2,
             int* __restrict__ eidx1, int* __restrict__ eidx2,
             int E1, int E2,
             const float* __restrict__ x, unsigned short* __restrict__ xb,
             const float* __restrict__ Wrel1, const float* __restrict__ Wroot1,
             unsigned short* __restrict__ Wt,
             const float* __restrict__ Wlin, const float* __restrict__ Whead,
             float* __restrict__ P1,
             int epb) {
    __shared__ float sh[5120];   // 20 KB: Whead tile / transpose tile
    int b = blockIdx.x;
    const int tid = threadIdx.x;
    if (b < 20) {                            // ---- P1 = Wlin @ Whead ----
        for (int i = tid; i < HH * C; i += 256) sh[i] = Whead[i];
        __syncthreads();
        int g = b * 256 + tid;               // 0..5119
        int k = g / C, c = g % C;
        const float4* rp = (const float4*)(Wlin + (size_t)k * HH);
        float a0 = 0.f, a1 = 0.f, a2 = 0.f, a3 = 0.f;
#pragma unroll 4
        for (int j = 0; j < HH / 4; ++j) {
            float4 v = rp[j];
            int j4 = j * 4;
            a0 += v.x * sh[(j4    ) * C + c];
            a1 += v.y * sh[(j4 + 1) * C + c];
            a2 += v.z * sh[(j4 + 2) * C + c];
            a3 += v.w * sh[(j4 + 3) * C + c];
        }
        P1[g] = (a0 + a1) + (a2 + a3);
        return;
    }
    b -= 20;
    if (b < 512) {                           // ---- weight transpose+cast ----
        int z = b >> 8, rem = b & 255;
        int bx = (rem & 15) * 32, by = (rem >> 4) * 32;
        const float* W = z ? Wroot1 : Wrel1;
        unsigned short* O = Wt + (size_t)z * HH * HH;
        int tx = tid & 31, ty = tid >> 5;
#pragma unroll
        for (int i = 0; i < 4; ++i)
            sh[(ty + i * 8) * 33 + tx] = W[(size_t)(by + ty + i * 8) * HH + bx + tx];
        __syncthreads();
#pragma unroll
        for (int i = 0; i < 4; ++i)
            O[(size_t)(bx + ty + i * 8) * HH + by + tx] = f2bf(sh[tx * 33 + ty + i * 8]);
        return;
    }
    b -= 512;
    {                   // ---- fused: edge count&place (epb/blk) + x cast ----
        int eg = b * epb + tid;
        bool hasE = (tid < epb) && (eg < E1 + E2);
        if (hasE) {
            if (eg < E1) {
                int d = dst1[eg];
                int pos = atomicAdd(&cnt1[d], 1);
                if (pos < SLOT) eidx1[d * SLOT + pos] = src1[eg];
            } else {
                int g2 = eg - E1;
                int d = dst2[g2];
                int pos = atomicAdd(&cnt2[d], 1);
                if (pos < SLOT) eidx2[d * SLOT + pos] = src2[g2];
            }
        }
        int g = b * 256 + tid;               // 16 floats per thread
        const float4* p = (const float4*)x + (size_t)g * 4;
        float4 v0 = p[0], v1 = p[1], v2 = p[2], v3 = p[3];
        unsigned short t[16] = {f2bf(v0.x), f2bf(v0.y), f2bf(v0.z), f2bf(v0.w),
                                f2bf(v1.x), f2bf(v1.y), f2bf(v1.z), f2bf(v1.w),
                                f2bf(v2.x), f2bf(v2.y), f2bf(v2.z), f2bf(v2.w),
                                f2bf(v3.x), f2bf(v3.y), f2bf(v3.z), f2bf(v3.w)};
        uint4* o = (uint4*)(xb + (size_t)g * 16);
        o[0] = ((const uint4*)t)[0];
        o[1] = ((const uint4*)t)[1];
    }
}

// ---------------- prep2: W2aT/W2bT + bout (R9 form) ----------------
__global__ __launch_bounds__(1024)
void prep2_k(const float* __restrict__ Wrel2, const float* __restrict__ Wroot2,
             const float* __restrict__ P1,
             const float* __restrict__ brel2, const float* __restrict__ blin,
             const float* __restrict__ Whead, const float* __restrict__ bhead,
             float* __restrict__ W2aT, float* __restrict__ W2bT,
             float* __restrict__ bout) {
    __shared__ float fsh[5120];              // 20 KB: P1 tile / reduce
    int blk = blockIdx.x;
    int t = threadIdx.x;
    if (blk < 10) {                          // ---- W2aT / W2bT (P1 staged in LDS) ----
        for (int i = t; i < HH * C; i += 1024) fsh[i] = P1[i];
        __syncthreads();
        int z = blk >= 5;
        int g = (blk - z * 5) * 1024 + t;
        if (g < HH * C) {
            const float* W = z ? Wroot2 : Wrel2;
            float* O = z ? W2bT : W2aT;
            int k = g / C, c = g % C;
            const float4* rp = (const float4*)(W + (size_t)k * HH);
            float a0 = 0.f, a1 = 0.f, a2 = 0.f, a3 = 0.f;
#pragma unroll 4
            for (int j = 0; j < HH / 4; ++j) {
                float4 v = rp[j];
                int j4 = j * 4;
                a0 += v.x * fsh[(j4    ) * C + c];
                a1 += v.y * fsh[(j4 + 1) * C + c];
                a2 += v.z * fsh[(j4 + 2) * C + c];
                a3 += v.w * fsh[(j4 + 3) * C + c];
            }
            O[c * HH + k] = (a0 + a1) + (a2 + a3);   // transposed [10][512]
        }
        return;
    }
    {                                        // ---- bout: parallel over j + reduce ----
        float pr[C];
#pragma unroll
        for (int c = 0; c < C; ++c) pr[c] = 0.f;
        if (t < HH) {
            float br = brel2[t], bl = blin[t];
            const float* p1r = P1 + (size_t)t * C;
            const float* whr = Whead + (size_t)t * C;
#pragma unroll
            for (int c = 0; c < C; ++c) pr[c] = br * p1r[c] + bl * whr[c];
        }
#pragma unroll
        for (int c = 0; c < C; ++c)
#pragma unroll
            for (int off = 32; off; off >>= 1) pr[c] += __shfl_xor(pr[c], off);
        int wv = t >> 6, ln = t & 63;
        if (ln == 0)
#pragma unroll
            for (int c = 0; c < C; ++c) fsh[wv * C + c] = pr[c];
        __syncthreads();
        if (t < C) {
            float acc = bhead[t];
#pragma unroll
            for (int w = 0; w < 16; ++w) acc += fsh[w * C + t];
            bout[t] = acc;
        }
    }
}

// ---- aggregation: one wave per node, slot CSR, int32 fixed-point (x2^20) ----
__global__ __launch_bounds__(256)
void agg_bf16_k(const unsigned short* __restrict__ x, const int* __restrict__ cnt,
                const int* __restrict__ eidx, unsigned short* __restrict__ out, int n) {
    int node = blockIdx.x * 4 + (threadIdx.x >> 6);
    if (node >= n) return;
    int l = threadIdx.x & 63;
    int deg = min(cnt[node], SLOT);
    const int* ep = eidx + (size_t)node * SLOT;
    int acc[8] = {};
    int i = 0;
    for (; i + 8 <= deg; i += 8) {
        uint4 v[8];
#pragma unroll
        for (int u = 0; u < 8; ++u)
            v[u] = *(const uint4*)(x + (size_t)ep[i + u] * HH + l * 8);
#pragma unroll
        for (int u = 0; u < 8; ++u) {
            const unsigned short* pv = (const unsigned short*)&v[u];
#pragma unroll
            for (int j = 0; j < 8; ++j) acc[j] += (int)(bf2f(pv[j]) * 1048576.0f);
        }
    }
    for (; i < deg; ++i) {
        uint4 a = *(const uint4*)(x + (size_t)ep[i] * HH + l * 8);
        const unsigned short* pa = (const unsigned short*)&a;
#pragma unroll
        for (int j = 0; j < 8; ++j) acc[j] += (int)(bf2f(pa[j]) * 1048576.0f);
    }
    unsigned short o[8];
#pragma unroll
    for (int j = 0; j < 8; ++j)
        o[j] = f2bf((float)acc[j] * (1.0f / 1048576.0f));
    *(uint4*)(out + (size_t)node * HH + l * 8) = *(const uint4*)o;
}

// ---- bf16 MFMA GEMM (layer 1, dual fused) + head-projection epilogue ----
__global__ __launch_bounds__(256)
void gemm_mfma_k(const short* __restrict__ A1, const short* __restrict__ B1t,
                 const short* __restrict__ A2, const short* __restrict__ B2t,
                 const float* __restrict__ bias,
                 const float* __restrict__ W2aT, const float* __restrict__ W2bT,
                 int* __restrict__ uA, int* __restrict__ vA) {
    __shared__ __align__(16) short Ls[4 * 128 * 32];   // staging / h-tile (32 KB)
    __shared__ float wshA[C * 128], wshB[C * 128];     // W2 slices (10 KB)
    short* As1 = Ls;
    short* As2 = Ls + 4096;
    short* Bs1 = Ls + 8192;
    short* Bs2 = Ls + 12288;
    const int bn = blockIdx.x * 128;
    const int bm = blockIdx.y * 128;
    const int tid = threadIdx.x;
    const int lane = tid & 63;
    const int wave = tid >> 6;
    const int l15 = lane & 15;
    const int quad = lane >> 4;
    const int wm = (wave >> 1) * 64;
    const int wn = (wave & 1) * 64;
    const int r0 = tid >> 2;          // 0..63
    const int sg = (tid & 3) * 8;     // bf16 offset in 32-k row

    // stage W2 column slices (f32) — covered by the k-loop's first barrier
    for (int i = tid; i < C * 128; i += 256) {
        int c = i >> 7, k = i & 127;
        wshA[i] = W2aT[c * HH + bn + k];
        wshB[i] = W2bT[c * HH + bn + k];
    }

    f32x4 acc[4][4] = {};

    for (int k0 = 0; k0 < 512; k0 += 32) {
        gld16(A1 + (size_t)(bm + r0) * 512 + k0 + sg,        As1 + tid * 8);
        gld16(A1 + (size_t)(bm + r0 + 64) * 512 + k0 + sg,   As1 + (tid + 256) * 8);
        gld16(A2 + (size_t)(bm + r0) * 512 + k0 + sg,        As2 + tid * 8);
        gld16(A2 + (size_t)(bm + r0 + 64) * 512 + k0 + sg,   As2 + (tid + 256) * 8);
        gld16(B1t + (size_t)(bn + r0) * 512 + k0 + sg,       Bs1 + tid * 8);
        gld16(B1t + (size_t)(bn + r0 + 64) * 512 + k0 + sg,  Bs1 + (tid + 256) * 8);
        gld16(B2t + (size_t)(bn + r0) * 512 + k0 + sg,       Bs2 + tid * 8);
        gld16(B2t + (size_t)(bn + r0 + 64) * 512 + k0 + sg,  Bs2 + (tid + 256) * 8);
        __syncthreads();
        {
            frag a[4], b[4];
#pragma unroll
            for (int mi = 0; mi < 4; ++mi)
                a[mi] = *(const frag*)(As1 + (wm + mi * 16 + l15) * 32 + quad * 8);
#pragma unroll
            for (int ni = 0; ni < 4; ++ni)
                b[ni] = *(const frag*)(Bs1 + (wn + ni * 16 + l15) * 32 + quad * 8);
#pragma unroll
            for (int mi = 0; mi < 4; ++mi)
#pragma unroll
                for (int ni = 0; ni < 4; ++ni)
                    acc[mi][ni] = __builtin_amdgcn_mfma_f32_16x16x32_bf16(
                        a[mi], b[ni], acc[mi][ni], 0, 0, 0);
#pragma unroll
            for (int mi = 0; mi < 4; ++mi)
                a[mi] = *(const frag*)(As2 + (wm + mi * 16 + l15) * 32 + quad * 8);
#pragma unroll
            for (int ni = 0; ni < 4; ++ni)
                b[ni] = *(const frag*)(Bs2 + (wn + ni * 16 + l15) * 32 + quad * 8);
#pragma unroll
            for (int mi = 0; mi < 4; ++mi)
#pragma unroll
                for (int ni = 0; ni < 4; ++ni)
                    acc[mi][ni] = __builtin_amdgcn_mfma_f32_16x16x32_bf16(
                        a[mi], b[ni], acc[mi][ni], 0, 0, 0);
        }
        __syncthreads();
    }

    // ---- epilogue 1: h-tile (bias+relu, bf16) into LDS [128][128] ----
#pragma unroll
    for (int ni = 0; ni < 4; ++ni) {
        const int lc = wn + ni * 16 + l15;
        const float bv = bias[bn + lc];
#pragma unroll
        for (int mi = 0; mi < 4; ++mi) {
            const int lr0 = wm + mi * 16 + quad * 4;
#pragma unroll
            for (int r = 0; r < 4; ++r)
                Ls[(lr0 + r) * 128 + lc] = (short)f2bf(fmaxf(acc[mi][ni][r] + bv, 0.f));
        }
    }
    __syncthreads();

    // ---- epilogue 2: per-row dots vs W2 slices -> int partials ----
    const int lr = tid >> 1;
    const int half = tid & 1;
    const int gm = bm + lr;
    const bool doV = (gm < N2);
    float pu[C], pv[C];
#pragma unroll
    for (int c = 0; c < C; ++c) { pu[c] = 0.f; pv[c] = 0.f; }
    const uint4* hrow = (const uint4*)(Ls + lr * 128 + half * 64);
    for (int ch = 0; ch < 8; ++ch) {
        uint4 hv = hrow[ch];
        const unsigned short* ph = (const unsigned short*)&hv;
        float f[8];
#pragma unroll
        for (int j = 0; j < 8; ++j) f[j] = bf2f(ph[j]);
        const int cb = half * 64 + ch * 8;
#pragma unroll
        for (int c = 0; c < C; ++c) {
            const float* wa = &wshA[c * 128 + cb];
            float4 w0 = *(const float4*)wa, w1 = *(const float4*)(wa + 4);
            pu[c] += f[0] * w0.x + f[1] * w0.y + f[2] * w0.z + f[3] * w0.w
                   + f[4] * w1.x + f[5] * w1.y + f[6] * w1.z + f[7] * w1.w;
        }
        if (doV) {
#pragma unroll
            for (int c = 0; c < C; ++c) {
                const float* wb = &wshB[c * 128 + cb];
                float4 w0 = *(const float4*)wb, w1 = *(const float4*)(wb + 4);
                pv[c] += f[0] * w0.x + f[1] * w0.y + f[2] * w0.z + f[3] * w0.w
                       + f[4] * w1.x + f[5] * w1.y + f[6] * w1.z + f[7] * w1.w;
            }
        }
    }
#pragma unroll
    for (int c = 0; c < C; ++c) pu[c] += __shfl_xor(pu[c], 1);
#pragma unroll
    for (int c = 0; c < C; ++c) pv[c] += __shfl_xor(pv[c], 1);
    if (half == 0 && gm < N1) {
        int* up = uA + ((size_t)blockIdx.x * N1 + gm) * C;
#pragma unroll
        for (int c = 0; c < C; ++c) up[c] = (int)(pu[c] * FIX);
        if (doV) {
            int* vp = vA + ((size_t)blockIdx.x * N2 + gm) * C;
#pragma unroll
            for (int c = 0; c < C; ++c) vp[c] = (int)(pv[c] * FIX);
        }
    }
}

// ---- tail2: out[n][c] = fix(sum_edges sum_p uA) + fix(sum_p vA) + bout[c] ----
__global__ __launch_bounds__(256)
void tail2_k(const int* __restrict__ cnt2, const int* __restrict__ eidx2,
             const int* __restrict__ uA, const int* __restrict__ vA,
             const float* __restrict__ bout, float* __restrict__ out) {
    int t = blockIdx.x * 256 + threadIdx.x;
    if (t >= N2 * C) return;
    int n = t / C;
    int c = t - n * C;
    int deg = min(cnt2[n], SLOT);
    const int* ep = eidx2 + (size_t)n * SLOT;
    int acc = 0;
    for (int i = 0; i < deg; ++i) {
        int j = ep[i] * C + c;
        acc += uA[j] + uA[N1 * C + j] + uA[2 * N1 * C + j] + uA[3 * N1 * C + j];
    }
    int vacc = vA[t] + vA[N2 * C + t] + vA[2 * N2 * C + t] + vA[3 * N2 * C + t];
    out[t] = (float)acc * FIXINV + (float)vacc * FIXINV + bout[c];
}

extern "C" void kernel_launch(void* const* d_in, const int* in_sizes, int n_in,
                              void* d_out, int out_size, void* d_ws, size_t ws_size,
                              hipStream_t stream) {
    const float* x      = (const float*)d_in[0];
    const int*   src1   = (const int*)d_in[1];
    const int*   dst1   = (const int*)d_in[2];
    const int*   src2   = (const int*)d_in[3];
    const int*   dst2   = (const int*)d_in[4];
    const float* Wrel1  = (const float*)d_in[5];
    const float* brel1  = (const float*)d_in[6];
    const float* Wroot1 = (const float*)d_in[7];
    const float* Wrel2  = (const float*)d_in[8];
    const float* brel2  = (const float*)d_in[9];
    const float* Wroot2 = (const float*)d_in[10];
    const float* Wlin   = (const float*)d_in[11];
    const float* blin   = (const float*)d_in[12];
    const float* Whead  = (const float*)d_in[13];
    const float* bhead  = (const float*)d_in[14];
    float* out = (float*)d_out;

    const int E1 = in_sizes[1];
    const int E2 = in_sizes[3];

    // ---- workspace layout (~135 MB; ws ~800 MB) ----
    char* w = (char*)d_ws;
    auto alloc = [&](size_t bytes) { char* p = w; w += (bytes + 255) & ~(size_t)255; return p; };
    unsigned short* xb    = (unsigned short*)alloc((size_t)N0 * HH * 2);
    unsigned short* agg1b = (unsigned short*)alloc((size_t)M1PAD * HH * 2);
    unsigned short* Wt    = (unsigned short*)alloc((size_t)2 * HH * HH * 2);
    float* P1    = (float*)alloc((size_t)HH * C * 4);
    float* W2aT  = (float*)alloc((size_t)HH * C * 4);
    float* W2bT  = (float*)alloc((size_t)HH * C * 4);
    float* boutp = (float*)alloc(256);
    int*   uA    = (int*)alloc((size_t)4 * N1 * C * 4);
    int*   vA    = (int*)alloc((size_t)4 * N2 * C * 4);
    int* cnt1  = (int*)alloc((size_t)(N1 + N2) * 4);   // cnt1 | cnt2 contiguous
    int* cnt2  = cnt1 + N1;
    int* eidx1 = (int*)alloc((size_t)N1 * SLOT * 4);
    int* eidx2 = (int*)alloc((size_t)N2 * SLOT * 4);

    const short* Wrel1t  = (const short*)(Wt);
    const short* Wroot1t = (const short*)(Wt + (size_t)HH * HH);

    hipMemsetAsync(cnt1, 0, (size_t)(N1 + N2) * sizeof(int), stream);

    // ---- prep1: P1 + castw + fused [castx + count&place] ----
    const int nbCast = N0 * HH / 16 / 256;   // 12500 (16 elem/thread)
    const int epb    = (E1 + E2 + nbCast - 1) / nbCast;   // ~48 edges per cast block
    prep1_k<<<20 + 512 + nbCast, 256, 0, stream>>>(
        src1, dst1, src2, dst2, cnt1, cnt2, eidx1, eidx2, E1, E2,
        x, xb, Wrel1, Wroot1, Wt, Wlin, Whead, P1, epb);

    // ---- prep2: W2aT/W2bT + bout ----
    prep2_k<<<11, 1024, 0, stream>>>(Wrel2, Wroot2, P1,
                                     brel2, blin, Whead, bhead, W2aT, W2bT, boutp);

    // ---- layer 1 aggregation ----
    agg_bf16_k<<<(N1 + 3) / 4, 256, 0, stream>>>(xb, cnt1, eidx1, agg1b, N1);

    // ---- layer-1 GEMM + fused head projection ----
    {
        dim3 grid(HH / 128, M1PAD / 128);
        gemm_mfma_k<<<grid, 256, 0, stream>>>(
            (const short*)agg1b, Wrel1t, (const short*)xb, Wroot1t, brel1,
            W2aT, W2bT, uA, vA);
    }

    // ---- layer-2 aggregation over 10-dim int partials + epilogue ----
    tail2_k<<<(N2 * C + 255) / 256, 256, 0, stream>>>(cnt2, eidx2, uA, vA, boutp, out);
}